// Round 9
// baseline (362.891 us; speedup 1.0000x reference)
//
#include <hip/hip_runtime.h>
#include <hip/hip_bf16.h>
#include <stdint.h>

typedef __bf16 bf16x8 __attribute__((ext_vector_type(8)));
typedef float f32x4 __attribute__((ext_vector_type(4)));
typedef float fvec4 __attribute__((ext_vector_type(4)));
typedef unsigned short usvec4 __attribute__((ext_vector_type(4)));
typedef unsigned int ui32x4 __attribute__((ext_vector_type(4)));

#define AS3 __attribute__((address_space(3)))
#define AS1 __attribute__((address_space(1)))

static __device__ __forceinline__ unsigned short f2bf(float f) {
  unsigned int u = __float_as_uint(f);
  u += 0x7FFF + ((u >> 16) & 1);   // round-to-nearest-even
  return (unsigned short)(u >> 16);
}

// ---------------- fp32 -> bf16 conversion kernels ----------------

extern "C" __global__ void cvt_bf16_kernel(const float* __restrict__ src,
                                           unsigned short* __restrict__ dst,
                                           long n4) {
  long i = (long)blockIdx.x * blockDim.x + threadIdx.x;
  const long stride = (long)gridDim.x * blockDim.x;
  for (; i < n4; i += stride) {
    const fvec4 v = __builtin_nontemporal_load(&((const fvec4*)src)[i]);
    usvec4 o;
    o.x = f2bf(v.x); o.y = f2bf(v.y); o.z = f2bf(v.z); o.w = f2bf(v.w);
    ((usvec4*)dst)[i] = o;
  }
}

extern "C" __global__ void cvt_pad_kernel(const float* __restrict__ src,
                                          unsigned short* __restrict__ dst,
                                          long nsrc4, long ntot4) {
  long i = (long)blockIdx.x * blockDim.x + threadIdx.x;
  const long stride = (long)gridDim.x * blockDim.x;
  for (; i < ntot4; i += stride) {
    usvec4 o = {0, 0, 0, 0};
    if (i < nsrc4) {
      const fvec4 v = __builtin_nontemporal_load(&((const fvec4*)src)[i]);
      o.x = f2bf(v.x); o.y = f2bf(v.y); o.z = f2bf(v.z); o.w = f2bf(v.w);
    }
    ((usvec4*)dst)[i] = o;
  }
}

#define VMW(N) asm volatile("s_waitcnt vmcnt(" #N ")" ::: "memory")
#define BAR() do { __builtin_amdgcn_s_barrier(); \
                   __builtin_amdgcn_sched_barrier(0); } while (0)
#define LGKM0() do { asm volatile("s_waitcnt lgkmcnt(0)" ::: "memory"); \
                     __builtin_amdgcn_sched_barrier(0); } while (0)

// ============ launch1 kernel: 256x256, BK=64, round-8 structure ============
// (unchanged — measured ~58% MfmaUtil at T=64, 256 blocks = 1 exact round)

template <int MODE>
__global__ __launch_bounds__(512, 2)
void mla_gemm(const __hip_bfloat16* __restrict__ A0p,
              const __hip_bfloat16* __restrict__ B0p, int K0,
              unsigned short* __restrict__ qlora,
              const float* __restrict__ cosp,
              const float* __restrict__ sinp,
              float* __restrict__ out) {
  extern __shared__ __align__(128) char lds[];
  const int tid = threadIdx.x;
  const int lane = tid & 63;
  const int w = tid >> 6;
  const int wm = w >> 2, wn = w & 3;
  const int l15 = lane & 15, lhi = lane >> 4;
  const int srow8 = lane >> 3;
  const int swzc = ((lane & 7) ^ srow8) * 8;

  const int swz = ((int)blockIdx.x & 7) * 32 + ((int)blockIdx.x >> 3);
  const int bm = swz >> 3, bn = swz & 7;
  const __hip_bfloat16* Aptr = A0p;
  const __hip_bfloat16* Bptr = B0p;
  const int K = K0;
  const long brow = (long)bm * 256;
  const int bcol = bn * 256;

  const __hip_bfloat16* aSt = Aptr + (brow + w * 16 + srow8) * (long)K + swzc;
  const __hip_bfloat16* bSt = Bptr + ((long)bcol + srow8) * (long)K + swzc;
  const int wj0 = w * 16, wj1 = w * 16 + 8;
  const int cb_j0 = (2 * (wj0 >> 5)) * 32 + (wj0 & 31);
  const int cb_j1 = (2 * (wj1 >> 5)) * 32 + (wj1 & 31);
  const int ldsWj = w * 2048;

  const int aRdRow = (wm * 64 + l15) * 128;
  const int bRdRow = (wn * 32 + l15) * 128;
  const int ck0 = (lhi ^ (l15 & 7)) * 16;

  f32x4 acc[8][4] = {};
  bf16x8 aF[4][2];
  bf16x8 bF[2][2][2];

  const int T = K >> 6;

  auto stage = [&](int u, int kt) {
    const int b = kt & 1;
    if (u < 2) {
      const int off = b * 32768 + u * 16384 + ldsWj;
      __builtin_amdgcn_global_load_lds((AS1 void*)(aSt + (long)(u * 128) * K + kt * 64),
                                       (AS3 void*)(lds + off), 16, 0, 0);
      __builtin_amdgcn_global_load_lds((AS1 void*)(aSt + (long)(u * 128 + 8) * K + kt * 64),
                                       (AS3 void*)(lds + off + 1024), 16, 0, 0);
    } else {
      const int h = u - 2;
      const int off = 65536 + b * 32768 + h * 16384 + ldsWj;
      __builtin_amdgcn_global_load_lds((AS1 void*)(bSt + (long)(cb_j0 + h * 32) * K + kt * 64),
                                       (AS3 void*)(lds + off), 16, 0, 0);
      __builtin_amdgcn_global_load_lds((AS1 void*)(bSt + (long)(cb_j1 + h * 32) * K + kt * 64),
                                       (AS3 void*)(lds + off + 1024), 16, 0, 0);
    }
  };
  auto readA = [&](int qh, int b) {
    const int base = b * 32768 + qh * 16384 + aRdRow;
    #pragma unroll
    for (int fr = 0; fr < 4; ++fr) {
      aF[fr][0] = *(const bf16x8*)(lds + base + fr * 2048 + ck0);
      aF[fr][1] = *(const bf16x8*)(lds + base + fr * 2048 + (ck0 ^ 64));
    }
  };
  auto readB = [&](int c, int b) {
    const int base = 65536 + b * 32768 + c * 16384 + bRdRow;
    #pragma unroll
    for (int fq = 0; fq < 2; ++fq) {
      bF[c][fq][0] = *(const bf16x8*)(lds + base + fq * 2048 + ck0);
      bF[c][fq][1] = *(const bf16x8*)(lds + base + fq * 2048 + (ck0 ^ 64));
    }
  };
  auto mmac = [&](int qh, int c) {
    __builtin_amdgcn_s_setprio(1);
    #pragma unroll
    for (int fr = 0; fr < 4; ++fr)
      #pragma unroll
      for (int fq = 0; fq < 2; ++fq) {
        acc[qh * 4 + fr][c * 2 + fq] = __builtin_amdgcn_mfma_f32_16x16x32_bf16(
            aF[fr][0], bF[c][fq][0], acc[qh * 4 + fr][c * 2 + fq], 0, 0, 0);
        acc[qh * 4 + fr][c * 2 + fq] = __builtin_amdgcn_mfma_f32_16x16x32_bf16(
            aF[fr][1], bF[c][fq][1], acc[qh * 4 + fr][c * 2 + fq], 0, 0, 0);
      }
    __builtin_amdgcn_s_setprio(0);
  };

  stage(0, 0); stage(2, 0); stage(3, 0); stage(1, 0);
  stage(0, 1); stage(2, 1); stage(3, 1); stage(1, 1);
  VMW(12);
  BAR();

  for (int t = 0; t < T - 2; ++t) {
    const int b = t & 1;
    readA(0, b); readB(0, b); if (t) stage(1, t + 1);
    VMW(10); BAR(); LGKM0(); mmac(0, 0);
    readB(1, b);
    VMW(8); BAR(); LGKM0(); mmac(0, 1);
    readA(1, b); stage(0, t + 2); stage(2, t + 2);
    BAR(); LGKM0(); mmac(1, 1);
    stage(3, t + 2);
    VMW(10); BAR(); mmac(1, 0);
  }
  {
    const int b = (T - 2) & 1;
    readA(0, b); readB(0, b); stage(1, T - 1);
    VMW(10); BAR(); LGKM0(); mmac(0, 0);
    readB(1, b);
    VMW(8); BAR(); LGKM0(); mmac(0, 1);
    readA(1, b);
    BAR(); LGKM0(); mmac(1, 1);
    VMW(4); BAR(); mmac(1, 0);
  }
  {
    const int b = (T - 1) & 1;
    readA(0, b); readB(0, b);
    VMW(2); BAR(); LGKM0(); mmac(0, 0);
    readB(1, b);
    VMW(0); BAR(); LGKM0(); mmac(0, 1);
    readA(1, b);
    BAR(); LGKM0(); mmac(1, 1);
    BAR(); mmac(1, 0);
  }

  const int wcol = bcol + wn * 64;
  const long rbase = brow + wm * 64;
  char* eplds = lds + w * 4096;

  auto storeTileF32 = [&](int i8, float* dst) {
    #pragma unroll
    for (int j = 0; j < 4; ++j)
      #pragma unroll
      for (int r = 0; r < 4; ++r)
        *(float*)(eplds + (lhi * 4 + r) * 256 + ((j >> 1) * 32 + (j & 1) * 16 + l15) * 4) =
            acc[i8][j][r];
    asm volatile("s_waitcnt lgkmcnt(0)" ::: "memory");
    #pragma unroll
    for (int t = 0; t < 4; ++t) {
      const int r16 = t * 4 + (lane >> 4);
      const f32x4 v = *(const f32x4*)(eplds + r16 * 256 + (lane & 15) * 16);
      const long row = rbase + (i8 >> 2) * 128 + (i8 & 3) * 16 + r16;
      __builtin_nontemporal_store(v, (f32x4*)(dst + row * 6720 + (lane & 15) * 4));
    }
  };
  auto storeTileBf16 = [&](int i8) {
    #pragma unroll
    for (int j = 0; j < 4; ++j)
      #pragma unroll
      for (int r = 0; r < 4; ++r)
        *(unsigned short*)(eplds + (lhi * 4 + r) * 128 +
                           ((j >> 1) * 32 + (j & 1) * 16 + l15) * 2) = f2bf(acc[i8][j][r]);
    asm volatile("s_waitcnt lgkmcnt(0)" ::: "memory");
    #pragma unroll
    for (int t = 0; t < 2; ++t) {
      const int r16 = t * 8 + (lane >> 3);
      const ui32x4 v = *(const ui32x4*)(eplds + r16 * 128 + (lane & 7) * 16);
      const long row = rbase + (i8 >> 2) * 128 + (i8 & 3) * 16 + r16;
      *(ui32x4*)((char*)qlora + (row * 1536 + wcol) * 2 + (lane & 7) * 16) = v;
    }
  };

  if (wcol < 1536) {
    #pragma unroll
    for (int i8 = 0; i8 < 8; ++i8) storeTileBf16(i8);
  } else {
    #pragma unroll
    for (int i8 = 0; i8 < 8; ++i8) storeTileF32(i8, out + wcol + 4672);
  }
}

// ============ launch2 kernel: 256x128, BK=32, 3-buf, 2 blocks/CU ============
// 8 waves 4Mx2N, wave tile 64x64, acc = 64 VGPR -> <=128 regs/wave with
// __launch_bounds__(512,4); LDS = 3 bufs x (A 16KB + B 8KB) = 72KB.
// => 2 blocks resident/CU: epilogue drain, prologue, barrier skew of one
// block overlap the other block's compute.
// Per tile: {8 ds_read_b128; stage tile t+2 (3 gloads -> buf (t+2)%3, never
// the buffer being read); VMW(3) [tile t+1's stages landed, t+2's in flight];
// LGKM0 BEFORE barrier (all waves' reads done -> next tile's stages into
// buf(t-1) are race-free); BAR; 16 MFMA}. vmcnt never 0 mid-loop.
// Swizzle (4 slots of 16B per 64B row): LDS[row][slot] holds global chunk
// slot^((row>>1)&3); reader uses slot = lhi^((l15>>1)&3) -> 2-way (free).
// First 32 blocks = k_pe (x @ w1 rows 2048..2175, K=4096, exact 128 cols).

__global__ __launch_bounds__(512, 4)
void mla_gemm2(const __hip_bfloat16* __restrict__ Aq,
               const __hip_bfloat16* __restrict__ Bq,
               const __hip_bfloat16* __restrict__ Ak,
               const __hip_bfloat16* __restrict__ Bk,
               const float* __restrict__ cosp,
               const float* __restrict__ sinp,
               float* __restrict__ out) {
  extern __shared__ __align__(128) char lds[];
  const int tid = threadIdx.x;
  const int lane = tid & 63;
  const int w = tid >> 6;
  const int wm = w >> 1, wn = w & 1;        // 4M x 2N
  const int l15 = lane & 15, lhi = lane >> 4;
  const int srow = lane >> 2;                       // staging row-in-16
  const int sslot = (lane & 3) ^ ((lane >> 3) & 3); // pre-swizzled src chunk

  const __hip_bfloat16* Ap;
  const __hip_bfloat16* Bp;
  int K, bm, bn;
  bool kpe;
  const int bid = (int)blockIdx.x;
  if (bid < 32) {
    kpe = true; bm = bid; bn = 0; Ap = Ak; Bp = Bk; K = 4096;
  } else {
    kpe = false;
    const int b2 = bid - 32;
    const int swz = (b2 & 7) * 192 + (b2 >> 3);   // 1536 blocks, bijective
    bm = swz / 48; bn = swz - bm * 48;
    Ap = Aq; Bp = Bq; K = 1536;
  }
  const long brow = (long)bm * 256;
  const int bcol = bn * 128;

  // staging: A 256x32 (16KB) = 2 gload rounds; B 128x32 (8KB) = 1 round.
  const __hip_bfloat16* aSt = Ap + (brow + w * 16 + srow) * (long)K + sslot * 8;
  const __hip_bfloat16* bSt = Bp + ((long)bcol + w * 16 + srow) * (long)K + sslot * 8;

  const int kslot = (lhi ^ ((l15 >> 1) & 3)) * 16;
  const int aRd = (wm * 64 + l15) * 64 + kslot;           // + fr*1024 + bufOff
  const int bRd = 16384 + (wn * 64 + l15) * 64 + kslot;   // + fc*1024 + bufOff

  f32x4 acc[4][4] = {};
  const int T = K >> 5;

  auto stage = [&](int kt, int buf) {
    const int bo = buf * 24576;
    __builtin_amdgcn_global_load_lds((AS1 void*)(aSt + (long)kt * 32),
                                     (AS3 void*)(lds + bo + w * 1024), 16, 0, 0);
    __builtin_amdgcn_global_load_lds((AS1 void*)(aSt + 128L * K + (long)kt * 32),
                                     (AS3 void*)(lds + bo + 8192 + w * 1024), 16, 0, 0);
    __builtin_amdgcn_global_load_lds((AS1 void*)(bSt + (long)kt * 32),
                                     (AS3 void*)(lds + bo + 16384 + w * 1024), 16, 0, 0);
  };

  // prologue: tiles 0 -> buf0, 1 -> buf1
  stage(0, 0); stage(1, 1);
  VMW(3);   // tile 0 landed (tile 1's 3 still in flight)
  BAR();

  int cur = 0;
  for (int t = 0; t < T; ++t) {
    const int bo = cur * 24576;
    bf16x8 aF[4], bF[4];
    #pragma unroll
    for (int f = 0; f < 4; ++f)
      aF[f] = *(const bf16x8*)(lds + bo + aRd + f * 1024);
    #pragma unroll
    for (int f = 0; f < 4; ++f)
      bF[f] = *(const bf16x8*)(lds + bo + bRd + f * 1024);
    if (t + 2 < T) {
      int nx = cur + 2; if (nx >= 3) nx -= 3;
      stage(t + 2, nx);
      VMW(3);
    } else if (t + 2 == T) {
      VMW(0);
    }
    LGKM0();
    if (t < T - 1) BAR();
    __builtin_amdgcn_s_setprio(1);
    #pragma unroll
    for (int fr = 0; fr < 4; ++fr)
      #pragma unroll
      for (int fc = 0; fc < 4; ++fc)
        acc[fr][fc] = __builtin_amdgcn_mfma_f32_16x16x32_bf16(
            aF[fr], bF[fc], acc[fr][fc], 0, 0, 0);
    __builtin_amdgcn_s_setprio(0);
    cur = cur + 1; if (cur == 3) cur = 0;
  }

  // ---- epilogue: LDS-transposed full-line stores (wave-local 4KB) ----
  // acc[fr][fc][r]: row = brow + wm*64 + fr*16 + lhi*4 + r,
  //                 col = bcol + wn*64 + fc*16 + l15.
  const int wcol = bcol + wn * 64;
  const long rbase = brow + wm * 64;
  char* eplds = lds + w * 4096;

  auto storeT = [&](int fr, int colBase, bool rope) {
    #pragma unroll
    for (int fc = 0; fc < 4; ++fc)
      #pragma unroll
      for (int r = 0; r < 4; ++r) {
        float v = acc[fr][fc][r];
        if (rope) {
          const long row = rbase + fr * 16 + lhi * 4 + r;
          const int d = fc * 16 + l15;
          const float rot = (fc < 2) ? -acc[fr][fc + 2][r] : acc[fr][fc - 2][r];
          v = v * cosp[row * 64 + d] + rot * sinp[row * 64 + d];
        }
        *(float*)(eplds + (lhi * 4 + r) * 256 + (fc * 16 + l15) * 4) = v;
      }
    asm volatile("s_waitcnt lgkmcnt(0)" ::: "memory");
    #pragma unroll
    for (int tt = 0; tt < 4; ++tt) {
      const int r16 = tt * 4 + (lane >> 4);
      const f32x4 vv = *(const f32x4*)(eplds + r16 * 256 + (lane & 15) * 16);
      const long row = rbase + fr * 16 + r16;
      __builtin_nontemporal_store(vv,
          (f32x4*)(out + row * 6720 + colBase + (lane & 15) * 4));
    }
  };

  if (kpe) {
    if (wn == 0) {   // cols 2048..2111 -> k_pe RoPE -> out 6144..6207
      #pragma unroll
      for (int fr = 0; fr < 4; ++fr) storeT(fr, 6144, true);
    }                // wn==1: pad cols 2112..2175, dropped
  } else if ((wcol % 192) == 128) {   // q_pe 64-block + RoPE
    #pragma unroll
    for (int fr = 0; fr < 4; ++fr) storeT(fr, wcol, true);
  } else {                            // q_nope copy
    #pragma unroll
    for (int fr = 0; fr < 4; ++fr) storeT(fr, wcol, false);
  }
}

// ---------------- launch ----------------

extern "C" void kernel_launch(void* const* d_in, const int* in_sizes, int n_in,
                              void* d_out, int out_size, void* d_ws, size_t ws_size,
                              hipStream_t stream) {
  const float* x    = (const float*)d_in[0];
  const float* cosp = (const float*)d_in[1];
  const float* sinp = (const float*)d_in[2];
  const float* Wqa  = (const float*)d_in[3];
  const float* Wqb  = (const float*)d_in[4];
  const float* Wkva = (const float*)d_in[5];
  float* out = (float*)d_out;

  char* ws = (char*)d_ws;
  __hip_bfloat16* xb  = (__hip_bfloat16*)ws;
  __hip_bfloat16* w1  = (__hip_bfloat16*)(ws + 67108864L);
  __hip_bfloat16* wqb = (__hip_bfloat16*)(ws + 67108864L + 17825792L);
  unsigned short* ql  = (unsigned short*)(ws + 67108864L + 17825792L + 18874368L);

  cvt_bf16_kernel<<<2048, 256, 0, stream>>>(x,   (unsigned short*)xb,  8192L * 4096 / 4);
  cvt_bf16_kernel<<<1024, 256, 0, stream>>>(Wqa, (unsigned short*)w1,  1536L * 4096 / 4);
  cvt_pad_kernel<<<640, 256, 0, stream>>>(Wkva, (unsigned short*)(w1 + 1536L * 4096),
                                          576L * 4096 / 4, 640L * 4096 / 4);
  cvt_bf16_kernel<<<1024, 256, 0, stream>>>(Wqb, (unsigned short*)wqb, 6144L * 1536 / 4);

  (void)hipFuncSetAttribute((const void*)&mla_gemm<0>,
                            hipFuncAttributeMaxDynamicSharedMemorySize, 131072);
  (void)hipFuncSetAttribute((const void*)&mla_gemm2,
                            hipFuncAttributeMaxDynamicSharedMemorySize, 73728);

  // launch1: x @ w1[0:2048] -> q_lora + compressed_kv. 256 blocks (1 round).
  mla_gemm<0><<<dim3(256), 512, 131072, stream>>>(xb, w1, 4096, ql, cosp, sinp, out);
  // launch2: 32 k_pe blocks (K=4096, LPT-first) + 1536 q blocks (K=1536),
  // 256x128 tiles, 2 blocks/CU.
  mla_gemm2<<<dim3(1568), 512, 73728, stream>>>((const __hip_bfloat16*)ql, wqb,
                                                xb, w1 + 2048L * 4096,
                                                cosp, sinp, out);
}

// Round 10
// 355.347 us; speedup vs baseline: 1.0212x; 1.0212x over previous
//
#include <hip/hip_runtime.h>
#include <hip/hip_bf16.h>
#include <stdint.h>

typedef __bf16 bf16x8 __attribute__((ext_vector_type(8)));
typedef float f32x4 __attribute__((ext_vector_type(4)));
typedef float fvec4 __attribute__((ext_vector_type(4)));
typedef unsigned short usvec4 __attribute__((ext_vector_type(4)));
typedef unsigned int ui32x4 __attribute__((ext_vector_type(4)));

#define AS3 __attribute__((address_space(3)))
#define AS1 __attribute__((address_space(1)))

static __device__ __forceinline__ unsigned short f2bf(float f) {
  unsigned int u = __float_as_uint(f);
  u += 0x7FFF + ((u >> 16) & 1);   // round-to-nearest-even
  return (unsigned short)(u >> 16);
}

// ---------------- fp32 -> bf16 conversion kernels ----------------

extern "C" __global__ void cvt_bf16_kernel(const float* __restrict__ src,
                                           unsigned short* __restrict__ dst,
                                           long n4) {
  long i = (long)blockIdx.x * blockDim.x + threadIdx.x;
  const long stride = (long)gridDim.x * blockDim.x;
  for (; i < n4; i += stride) {
    const fvec4 v = __builtin_nontemporal_load(&((const fvec4*)src)[i]);
    usvec4 o;
    o.x = f2bf(v.x); o.y = f2bf(v.y); o.z = f2bf(v.z); o.w = f2bf(v.w);
    ((usvec4*)dst)[i] = o;
  }
}

extern "C" __global__ void cvt_pad_kernel(const float* __restrict__ src,
                                          unsigned short* __restrict__ dst,
                                          long nsrc4, long ntot4) {
  long i = (long)blockIdx.x * blockDim.x + threadIdx.x;
  const long stride = (long)gridDim.x * blockDim.x;
  for (; i < ntot4; i += stride) {
    usvec4 o = {0, 0, 0, 0};
    if (i < nsrc4) {
      const fvec4 v = __builtin_nontemporal_load(&((const fvec4*)src)[i]);
      o.x = f2bf(v.x); o.y = f2bf(v.y); o.z = f2bf(v.z); o.w = f2bf(v.w);
    }
    ((usvec4*)dst)[i] = o;
  }
}

#define VMW(N) asm volatile("s_waitcnt vmcnt(" #N ")" ::: "memory")
#define BAR() do { __builtin_amdgcn_s_barrier(); \
                   __builtin_amdgcn_sched_barrier(0); } while (0)
#define LGKM0() do { asm volatile("s_waitcnt lgkmcnt(0)" ::: "memory"); \
                     __builtin_amdgcn_sched_barrier(0); } while (0)

// ============ launch1 kernel: 256x256, BK=64, round-8 structure ============
// Round-10 change: bn-major XCD swizzle — bn = bid&7 (= XCD id), so each XCD
// owns ONE B col-panel (2MB, L2-resident); A streams via L3.

template <int MODE>
__global__ __launch_bounds__(512, 2)
void mla_gemm(const __hip_bfloat16* __restrict__ A0p,
              const __hip_bfloat16* __restrict__ B0p, int K0,
              unsigned short* __restrict__ qlora,
              const float* __restrict__ cosp,
              const float* __restrict__ sinp,
              float* __restrict__ out) {
  extern __shared__ __align__(128) char lds[];
  const int tid = threadIdx.x;
  const int lane = tid & 63;
  const int w = tid >> 6;
  const int wm = w >> 2, wn = w & 3;
  const int l15 = lane & 15, lhi = lane >> 4;
  const int srow8 = lane >> 3;
  const int swzc = ((lane & 7) ^ srow8) * 8;

  const int bm = (int)blockIdx.x >> 3;     // bn-major: XCD id == bn
  const int bn = (int)blockIdx.x & 7;
  const __hip_bfloat16* Aptr = A0p;
  const __hip_bfloat16* Bptr = B0p;
  const int K = K0;
  const long brow = (long)bm * 256;
  const int bcol = bn * 256;

  const __hip_bfloat16* aSt = Aptr + (brow + w * 16 + srow8) * (long)K + swzc;
  const __hip_bfloat16* bSt = Bptr + ((long)bcol + srow8) * (long)K + swzc;
  const int wj0 = w * 16, wj1 = w * 16 + 8;
  const int cb_j0 = (2 * (wj0 >> 5)) * 32 + (wj0 & 31);
  const int cb_j1 = (2 * (wj1 >> 5)) * 32 + (wj1 & 31);
  const int ldsWj = w * 2048;

  const int aRdRow = (wm * 64 + l15) * 128;
  const int bRdRow = (wn * 32 + l15) * 128;
  const int ck0 = (lhi ^ (l15 & 7)) * 16;

  f32x4 acc[8][4] = {};
  bf16x8 aF[4][2];
  bf16x8 bF[2][2][2];

  const int T = K >> 6;

  auto stage = [&](int u, int kt) {
    const int b = kt & 1;
    if (u < 2) {
      const int off = b * 32768 + u * 16384 + ldsWj;
      __builtin_amdgcn_global_load_lds((AS1 void*)(aSt + (long)(u * 128) * K + kt * 64),
                                       (AS3 void*)(lds + off), 16, 0, 0);
      __builtin_amdgcn_global_load_lds((AS1 void*)(aSt + (long)(u * 128 + 8) * K + kt * 64),
                                       (AS3 void*)(lds + off + 1024), 16, 0, 0);
    } else {
      const int h = u - 2;
      const int off = 65536 + b * 32768 + h * 16384 + ldsWj;
      __builtin_amdgcn_global_load_lds((AS1 void*)(bSt + (long)(cb_j0 + h * 32) * K + kt * 64),
                                       (AS3 void*)(lds + off), 16, 0, 0);
      __builtin_amdgcn_global_load_lds((AS1 void*)(bSt + (long)(cb_j1 + h * 32) * K + kt * 64),
                                       (AS3 void*)(lds + off + 1024), 16, 0, 0);
    }
  };
  auto readA = [&](int qh, int b) {
    const int base = b * 32768 + qh * 16384 + aRdRow;
    #pragma unroll
    for (int fr = 0; fr < 4; ++fr) {
      aF[fr][0] = *(const bf16x8*)(lds + base + fr * 2048 + ck0);
      aF[fr][1] = *(const bf16x8*)(lds + base + fr * 2048 + (ck0 ^ 64));
    }
  };
  auto readB = [&](int c, int b) {
    const int base = 65536 + b * 32768 + c * 16384 + bRdRow;
    #pragma unroll
    for (int fq = 0; fq < 2; ++fq) {
      bF[c][fq][0] = *(const bf16x8*)(lds + base + fq * 2048 + ck0);
      bF[c][fq][1] = *(const bf16x8*)(lds + base + fq * 2048 + (ck0 ^ 64));
    }
  };
  auto mmac = [&](int qh, int c) {
    __builtin_amdgcn_s_setprio(1);
    #pragma unroll
    for (int fr = 0; fr < 4; ++fr)
      #pragma unroll
      for (int fq = 0; fq < 2; ++fq) {
        acc[qh * 4 + fr][c * 2 + fq] = __builtin_amdgcn_mfma_f32_16x16x32_bf16(
            aF[fr][0], bF[c][fq][0], acc[qh * 4 + fr][c * 2 + fq], 0, 0, 0);
        acc[qh * 4 + fr][c * 2 + fq] = __builtin_amdgcn_mfma_f32_16x16x32_bf16(
            aF[fr][1], bF[c][fq][1], acc[qh * 4 + fr][c * 2 + fq], 0, 0, 0);
      }
    __builtin_amdgcn_s_setprio(0);
  };

  stage(0, 0); stage(2, 0); stage(3, 0); stage(1, 0);
  stage(0, 1); stage(2, 1); stage(3, 1); stage(1, 1);
  VMW(12);
  BAR();

  for (int t = 0; t < T - 2; ++t) {
    const int b = t & 1;
    readA(0, b); readB(0, b); if (t) stage(1, t + 1);
    VMW(10); BAR(); LGKM0(); mmac(0, 0);
    readB(1, b);
    VMW(8); BAR(); LGKM0(); mmac(0, 1);
    readA(1, b); stage(0, t + 2); stage(2, t + 2);
    BAR(); LGKM0(); mmac(1, 1);
    stage(3, t + 2);
    VMW(10); BAR(); mmac(1, 0);
  }
  {
    const int b = (T - 2) & 1;
    readA(0, b); readB(0, b); stage(1, T - 1);
    VMW(10); BAR(); LGKM0(); mmac(0, 0);
    readB(1, b);
    VMW(8); BAR(); LGKM0(); mmac(0, 1);
    readA(1, b);
    BAR(); LGKM0(); mmac(1, 1);
    VMW(4); BAR(); mmac(1, 0);
  }
  {
    const int b = (T - 1) & 1;
    readA(0, b); readB(0, b);
    VMW(2); BAR(); LGKM0(); mmac(0, 0);
    readB(1, b);
    VMW(0); BAR(); LGKM0(); mmac(0, 1);
    readA(1, b);
    BAR(); LGKM0(); mmac(1, 1);
    BAR(); mmac(1, 0);
  }

  const int wcol = bcol + wn * 64;
  const long rbase = brow + wm * 64;
  char* eplds = lds + w * 4096;

  auto storeTileF32 = [&](int i8, float* dst) {
    #pragma unroll
    for (int j = 0; j < 4; ++j)
      #pragma unroll
      for (int r = 0; r < 4; ++r)
        *(float*)(eplds + (lhi * 4 + r) * 256 + ((j >> 1) * 32 + (j & 1) * 16 + l15) * 4) =
            acc[i8][j][r];
    asm volatile("s_waitcnt lgkmcnt(0)" ::: "memory");
    #pragma unroll
    for (int t = 0; t < 4; ++t) {
      const int r16 = t * 4 + (lane >> 4);
      const f32x4 v = *(const f32x4*)(eplds + r16 * 256 + (lane & 15) * 16);
      const long row = rbase + (i8 >> 2) * 128 + (i8 & 3) * 16 + r16;
      __builtin_nontemporal_store(v, (f32x4*)(dst + row * 6720 + (lane & 15) * 4));
    }
  };
  auto storeTileBf16 = [&](int i8) {
    #pragma unroll
    for (int j = 0; j < 4; ++j)
      #pragma unroll
      for (int r = 0; r < 4; ++r)
        *(unsigned short*)(eplds + (lhi * 4 + r) * 128 +
                           ((j >> 1) * 32 + (j & 1) * 16 + l15) * 2) = f2bf(acc[i8][j][r]);
    asm volatile("s_waitcnt lgkmcnt(0)" ::: "memory");
    #pragma unroll
    for (int t = 0; t < 2; ++t) {
      const int r16 = t * 8 + (lane >> 3);
      const ui32x4 v = *(const ui32x4*)(eplds + r16 * 128 + (lane & 7) * 16);
      const long row = rbase + (i8 >> 2) * 128 + (i8 & 3) * 16 + r16;
      *(ui32x4*)((char*)qlora + (row * 1536 + wcol) * 2 + (lane & 7) * 16) = v;
    }
  };

  if (wcol < 1536) {
    #pragma unroll
    for (int i8 = 0; i8 < 8; ++i8) storeTileBf16(i8);
  } else {
    #pragma unroll
    for (int i8 = 0; i8 < 8; ++i8) storeTileF32(i8, out + wcol + 4672);
  }
}

// ============ launch2 kernel: 256x128, BK=32, 3-buf, 2 blocks/CU ============
// Round-10 change: bn-major XCD mapping — XCD x owns bn in {6x..6x+5}; its
// active blocks share 6 B col-panels (2.3MB, stable in L2); A (ql, L3-warm
// from launch1) streams. Kills the B-panel L3-thrash refetch (~255MB).

__global__ __launch_bounds__(512, 4)
void mla_gemm2(const __hip_bfloat16* __restrict__ Aq,
               const __hip_bfloat16* __restrict__ Bq,
               const __hip_bfloat16* __restrict__ Ak,
               const __hip_bfloat16* __restrict__ Bk,
               const float* __restrict__ cosp,
               const float* __restrict__ sinp,
               float* __restrict__ out) {
  extern __shared__ __align__(128) char lds[];
  const int tid = threadIdx.x;
  const int lane = tid & 63;
  const int w = tid >> 6;
  const int wm = w >> 1, wn = w & 1;        // 4M x 2N
  const int l15 = lane & 15, lhi = lane >> 4;
  const int srow = lane >> 2;                       // staging row-in-16
  const int sslot = (lane & 3) ^ ((lane >> 3) & 3); // pre-swizzled src chunk

  const __hip_bfloat16* Ap;
  const __hip_bfloat16* Bp;
  int K, bm, bn;
  bool kpe;
  const int bid = (int)blockIdx.x;
  if (bid < 32) {
    kpe = true; bm = bid; bn = 0; Ap = Ak; Bp = Bk; K = 4096;
  } else {
    kpe = false;
    const int b2 = bid - 32;
    const int x = b2 & 7;          // XCD id (32 % 8 == 0 keeps alignment)
    const int i = b2 >> 3;         // 0..191 within XCD
    const int r6 = i % 6;
    bm = i / 6;                    // 0..31
    bn = x * 6 + r6;               // XCD x owns cols {6x..6x+5}
    Ap = Aq; Bp = Bq; K = 1536;
  }
  const long brow = (long)bm * 256;
  const int bcol = bn * 128;

  // staging: A 256x32 (16KB) = 2 gload rounds; B 128x32 (8KB) = 1 round.
  const __hip_bfloat16* aSt = Ap + (brow + w * 16 + srow) * (long)K + sslot * 8;
  const __hip_bfloat16* bSt = Bp + ((long)bcol + w * 16 + srow) * (long)K + sslot * 8;

  const int kslot = (lhi ^ ((l15 >> 1) & 3)) * 16;
  const int aRd = (wm * 64 + l15) * 64 + kslot;           // + fr*1024 + bufOff
  const int bRd = 16384 + (wn * 64 + l15) * 64 + kslot;   // + fc*1024 + bufOff

  f32x4 acc[4][4] = {};
  const int T = K >> 5;

  auto stage = [&](int kt, int buf) {
    const int bo = buf * 24576;
    __builtin_amdgcn_global_load_lds((AS1 void*)(aSt + (long)kt * 32),
                                     (AS3 void*)(lds + bo + w * 1024), 16, 0, 0);
    __builtin_amdgcn_global_load_lds((AS1 void*)(aSt + 128L * K + (long)kt * 32),
                                     (AS3 void*)(lds + bo + 8192 + w * 1024), 16, 0, 0);
    __builtin_amdgcn_global_load_lds((AS1 void*)(bSt + (long)kt * 32),
                                     (AS3 void*)(lds + bo + 16384 + w * 1024), 16, 0, 0);
  };

  // prologue: tiles 0 -> buf0, 1 -> buf1
  stage(0, 0); stage(1, 1);
  VMW(3);   // tile 0 landed (tile 1's 3 still in flight)
  BAR();

  int cur = 0;
  for (int t = 0; t < T; ++t) {
    const int bo = cur * 24576;
    bf16x8 aF[4], bF[4];
    #pragma unroll
    for (int f = 0; f < 4; ++f)
      aF[f] = *(const bf16x8*)(lds + bo + aRd + f * 1024);
    #pragma unroll
    for (int f = 0; f < 4; ++f)
      bF[f] = *(const bf16x8*)(lds + bo + bRd + f * 1024);
    if (t + 2 < T) {
      int nx = cur + 2; if (nx >= 3) nx -= 3;
      stage(t + 2, nx);
      VMW(3);
    } else if (t + 2 == T) {
      VMW(0);
    }
    LGKM0();
    if (t < T - 1) BAR();
    __builtin_amdgcn_s_setprio(1);
    #pragma unroll
    for (int fr = 0; fr < 4; ++fr)
      #pragma unroll
      for (int fc = 0; fc < 4; ++fc)
        acc[fr][fc] = __builtin_amdgcn_mfma_f32_16x16x32_bf16(
            aF[fr], bF[fc], acc[fr][fc], 0, 0, 0);
    __builtin_amdgcn_s_setprio(0);
    cur = cur + 1; if (cur == 3) cur = 0;
  }

  // ---- epilogue: LDS-transposed full-line stores (wave-local 4KB) ----
  // acc[fr][fc][r]: row = brow + wm*64 + fr*16 + lhi*4 + r,
  //                 col = bcol + wn*64 + fc*16 + l15.
  const int wcol = bcol + wn * 64;
  const long rbase = brow + wm * 64;
  char* eplds = lds + w * 4096;

  auto storeT = [&](int fr, int colBase, bool rope) {
    #pragma unroll
    for (int fc = 0; fc < 4; ++fc)
      #pragma unroll
      for (int r = 0; r < 4; ++r) {
        float v = acc[fr][fc][r];
        if (rope) {
          const long row = rbase + fr * 16 + lhi * 4 + r;
          const int d = fc * 16 + l15;
          const float rot = (fc < 2) ? -acc[fr][fc + 2][r] : acc[fr][fc - 2][r];
          v = v * cosp[row * 64 + d] + rot * sinp[row * 64 + d];
        }
        *(float*)(eplds + (lhi * 4 + r) * 256 + (fc * 16 + l15) * 4) = v;
      }
    asm volatile("s_waitcnt lgkmcnt(0)" ::: "memory");
    #pragma unroll
    for (int tt = 0; tt < 4; ++tt) {
      const int r16 = tt * 4 + (lane >> 4);
      const f32x4 vv = *(const f32x4*)(eplds + r16 * 256 + (lane & 15) * 16);
      const long row = rbase + fr * 16 + r16;
      __builtin_nontemporal_store(vv,
          (f32x4*)(out + row * 6720 + colBase + (lane & 15) * 4));
    }
  };

  if (kpe) {
    if (wn == 0) {   // cols 2048..2111 -> k_pe RoPE -> out 6144..6207
      #pragma unroll
      for (int fr = 0; fr < 4; ++fr) storeT(fr, 6144, true);
    }                // wn==1: pad cols 2112..2175, dropped
  } else if ((wcol % 192) == 128) {   // q_pe 64-block + RoPE
    #pragma unroll
    for (int fr = 0; fr < 4; ++fr) storeT(fr, wcol, true);
  } else {                            // q_nope copy
    #pragma unroll
    for (int fr = 0; fr < 4; ++fr) storeT(fr, wcol, false);
  }
}

// ---------------- launch ----------------

extern "C" void kernel_launch(void* const* d_in, const int* in_sizes, int n_in,
                              void* d_out, int out_size, void* d_ws, size_t ws_size,
                              hipStream_t stream) {
  const float* x    = (const float*)d_in[0];
  const float* cosp = (const float*)d_in[1];
  const float* sinp = (const float*)d_in[2];
  const float* Wqa  = (const float*)d_in[3];
  const float* Wqb  = (const float*)d_in[4];
  const float* Wkva = (const float*)d_in[5];
  float* out = (float*)d_out;

  char* ws = (char*)d_ws;
  __hip_bfloat16* xb  = (__hip_bfloat16*)ws;
  __hip_bfloat16* w1  = (__hip_bfloat16*)(ws + 67108864L);
  __hip_bfloat16* wqb = (__hip_bfloat16*)(ws + 67108864L + 17825792L);
  unsigned short* ql  = (unsigned short*)(ws + 67108864L + 17825792L + 18874368L);

  cvt_bf16_kernel<<<2048, 256, 0, stream>>>(x,   (unsigned short*)xb,  8192L * 4096 / 4);
  cvt_bf16_kernel<<<1024, 256, 0, stream>>>(Wqa, (unsigned short*)w1,  1536L * 4096 / 4);
  cvt_pad_kernel<<<640, 256, 0, stream>>>(Wkva, (unsigned short*)(w1 + 1536L * 4096),
                                          576L * 4096 / 4, 640L * 4096 / 4);
  cvt_bf16_kernel<<<1024, 256, 0, stream>>>(Wqb, (unsigned short*)wqb, 6144L * 1536 / 4);

  (void)hipFuncSetAttribute((const void*)&mla_gemm<0>,
                            hipFuncAttributeMaxDynamicSharedMemorySize, 131072);
  (void)hipFuncSetAttribute((const void*)&mla_gemm2,
                            hipFuncAttributeMaxDynamicSharedMemorySize, 73728);

  // launch1: x @ w1[0:2048] -> q_lora + compressed_kv. 256 blocks (1 round).
  mla_gemm<0><<<dim3(256), 512, 131072, stream>>>(xb, w1, 4096, ql, cosp, sinp, out);
  // launch2: 32 k_pe blocks (K=4096, LPT-first) + 1536 q blocks (K=1536),
  // 256x128 tiles, 2 blocks/CU, bn-major XCD locality.
  mla_gemm2<<<dim3(1568), 512, 73728, stream>>>((const __hip_bfloat16*)ql, wqb,
                                                xb, w1 + 2048L * 4096,
                                                cosp, sinp, out);
}